// Round 1
// baseline (2262.364 us; speedup 1.0000x reference)
//
#include <hip/hip_runtime.h>
#include <math.h>

#define N_NODES 50000
#define N_EDGES 800000
#define CH 128        // IN_CH = OUT_CH = MSG_DIM = TIME_DIM = 128
#define EDGE_DIM 256  // TIME_DIM + MSG_DIM

// ---------------------------------------------------------------------------
// Kernel A: node linears.  Q,K,V,S = x @ {Wq,Wk,Wv,Ws} + {bq,bk,bv,bs}
// 16 nodes per block, x-tile staged in LDS, each thread owns one output col
// for 8 nodes.  W rows are read coalesced (L2/L3-resident, 64 KB each).
// ---------------------------------------------------------------------------
__global__ __launch_bounds__(256) void node_linear_kernel(
    const float* __restrict__ x,
    const float* __restrict__ Wq, const float* __restrict__ bq,
    const float* __restrict__ Wk, const float* __restrict__ bk,
    const float* __restrict__ Wv, const float* __restrict__ bv,
    const float* __restrict__ Ws, const float* __restrict__ bs,
    float* __restrict__ Q, float* __restrict__ K,
    float* __restrict__ V, float* __restrict__ S)
{
    __shared__ float xs[16][CH];
    const int t  = threadIdx.x;
    const int n0 = blockIdx.x * 16;

    // load 16 x-rows (2048 floats) coalesced
    const float* xsrc = x + (size_t)n0 * CH;
    #pragma unroll
    for (int r = 0; r < 8; ++r) {
        int flat = r * 256 + t;
        xs[flat >> 7][flat & 127] = xsrc[flat];
    }
    __syncthreads();

    const int c    = t & 127;   // output column
    const int half = t >> 7;    // node half: 0 -> nodes 0..7, 1 -> 8..15

    const float* Wm[4] = {Wq, Wk, Wv, Ws};
    const float* Bm[4] = {bq, bk, bv, bs};
    float*       Om[4] = {Q,  K,  V,  S };

    for (int m = 0; m < 4; ++m) {
        const float* W = Wm[m];
        float acc[8];
        #pragma unroll
        for (int i = 0; i < 8; ++i) acc[i] = 0.f;
        for (int j = 0; j < CH; ++j) {
            float w = W[j * CH + c];
            #pragma unroll
            for (int i = 0; i < 8; ++i)
                acc[i] = fmaf(xs[half * 8 + i][j], w, acc[i]);
        }
        float  b = Bm[m][c];
        float* O = Om[m];
        #pragma unroll
        for (int i = 0; i < 8; ++i)
            O[(size_t)(n0 + half * 8 + i) * CH + c] = acc[i] + b;
    }
}

// ---------------------------------------------------------------------------
// Kernel B: fused per-edge pass.  64-edge tile per block (E = 12500 * 64).
//   1. build edge_attr tile in LDS:  [cos(rel_t*W_time+b_time) | msg]
//   2. register-tiled f32 GEMM  e_vec = edge_attr @ We  (thread: 8 edges x 4 ch)
//   3. alpha = q[dst]·(k[src]+e)/8 via 16-lane shuffle reduce; p = exp(alpha)
//      (max-free softmax: alpha is O(1) bounded, exp cannot overflow; the
//       normalized result is identical to the max-subtracted reference)
//   4. atomicAdd p into denom[dst,h]; atomicAdd p*(v[src]+e) into out numerator
// ---------------------------------------------------------------------------
__global__ __launch_bounds__(256) void edge_attn_kernel(
    const float* __restrict__ last_update,
    const float* __restrict__ t_arr,
    const float* __restrict__ msg,
    const int*   __restrict__ edge_index,   // [2][E] (int32)
    const float* __restrict__ W_time,       // [128]
    const float* __restrict__ b_time,       // [128]
    const float* __restrict__ We,           // [256][128]
    const float* __restrict__ Q,
    const float* __restrict__ K,
    const float* __restrict__ V,
    float* __restrict__ out_num,            // [N][128], numerator accumulator
    float* __restrict__ denom)              // [N][2]
{
    __shared__ float ea[64][EDGE_DIM + 1];  // +1 pad breaks bank aliasing
    __shared__ float relt[64];
    __shared__ int   ssrc[64], sdst[64];

    const int t   = threadIdx.x;
    const int e0g = blockIdx.x * 64;
    const int* srcp = edge_index;
    const int* dstp = edge_index + N_EDGES;

    if (t < 64) {
        int eg = e0g + t;
        int s  = srcp[eg];
        ssrc[t] = s;
        sdst[t] = dstp[eg];
        relt[t] = last_update[s] - t_arr[eg];
    }
    __syncthreads();

    // --- build edge_attr tile ---
    if (t < 128) {
        float wt = W_time[t];
        float bt = b_time[t];
        #pragma unroll 4
        for (int e = 0; e < 64; ++e)
            ea[e][t] = __cosf(fmaf(relt[e], wt, bt));
    } else {
        int c = t - 128;
        #pragma unroll 4
        for (int e = 0; e < 64; ++e)
            ea[e][128 + c] = msg[(size_t)(e0g + e) * CH + c];
    }
    __syncthreads();

    // --- GEMM: e_vec[e][c] = sum_j ea[e][j] * We[j][c] ---
    const int tx = t & 31;       // channel quad index (c0 = 4*tx)
    const int ey = t >> 5;       // edge group of 8
    const int c0 = tx * 4;
    const int e0 = ey * 8;

    float4 acc[8];
    #pragma unroll
    for (int i = 0; i < 8; ++i) acc[i] = make_float4(0.f, 0.f, 0.f, 0.f);

    for (int j = 0; j < EDGE_DIM; ++j) {
        float4 w = *(const float4*)(We + (size_t)j * CH + c0);
        #pragma unroll
        for (int i = 0; i < 8; ++i) {
            float a = ea[e0 + i][j];
            acc[i].x = fmaf(a, w.x, acc[i].x);
            acc[i].y = fmaf(a, w.y, acc[i].y);
            acc[i].z = fmaf(a, w.z, acc[i].z);
            acc[i].w = fmaf(a, w.w, acc[i].w);
        }
    }

    // --- attention + scatter ---
    const int head = tx >> 4;    // tx 0..15 -> head 0 (ch 0..63), 16..31 -> head 1
    #pragma unroll
    for (int i = 0; i < 8; ++i) {
        int e  = e0 + i;
        int sn = ssrc[e];
        int dn = sdst[e];
        const float4 k4 = *(const float4*)(K + (size_t)sn * CH + c0);
        const float4 q4 = *(const float4*)(Q + (size_t)dn * CH + c0);
        float part = q4.x * (k4.x + acc[i].x)
                   + q4.y * (k4.y + acc[i].y)
                   + q4.z * (k4.z + acc[i].z)
                   + q4.w * (k4.w + acc[i].w);
        // reduce over the 16 lanes covering this head (lane bits 0..3)
        part += __shfl_xor(part, 1);
        part += __shfl_xor(part, 2);
        part += __shfl_xor(part, 4);
        part += __shfl_xor(part, 8);
        float p = __expf(part * 0.125f);   // / sqrt(HEAD_C=64)

        if ((tx & 15) == 0)
            atomicAdd(denom + (size_t)dn * 2 + head, p);

        const float4 v4 = *(const float4*)(V + (size_t)sn * CH + c0);
        float* op = out_num + (size_t)dn * CH + c0;
        atomicAdd(op + 0, p * (v4.x + acc[i].x));
        atomicAdd(op + 1, p * (v4.y + acc[i].y));
        atomicAdd(op + 2, p * (v4.z + acc[i].z));
        atomicAdd(op + 3, p * (v4.w + acc[i].w));
    }
}

// ---------------------------------------------------------------------------
// Kernel C: out = num/denom + skip   (empty segments -> 0 + skip)
// ---------------------------------------------------------------------------
__global__ __launch_bounds__(256) void finalize_kernel(
    const float* __restrict__ S,
    const float* __restrict__ denom,
    float* __restrict__ out)
{
    int idx = blockIdx.x * 256 + threadIdx.x;   // over N*128
    int n = idx >> 7;
    int c = idx & 127;
    int h = c >> 6;
    float d   = denom[(size_t)n * 2 + h];
    float num = out[idx];
    float val = (d > 0.f) ? (num / d) : 0.f;
    out[idx] = val + S[idx];
}

extern "C" void kernel_launch(void* const* d_in, const int* in_sizes, int n_in,
                              void* d_out, int out_size, void* d_ws, size_t ws_size,
                              hipStream_t stream) {
    const float* x           = (const float*)d_in[0];
    const float* last_update = (const float*)d_in[1];
    const float* t           = (const float*)d_in[2];
    const float* msg         = (const float*)d_in[3];
    const int*   edge_index  = (const int*)d_in[4];
    const float* W_time      = (const float*)d_in[5];
    const float* b_time      = (const float*)d_in[6];
    const float* Wq = (const float*)d_in[7];
    const float* bq = (const float*)d_in[8];
    const float* Wk = (const float*)d_in[9];
    const float* bk = (const float*)d_in[10];
    const float* Wv = (const float*)d_in[11];
    const float* bv = (const float*)d_in[12];
    const float* We = (const float*)d_in[13];
    const float* Ws = (const float*)d_in[14];
    const float* bs = (const float*)d_in[15];
    float* out = (float*)d_out;

    float* ws = (float*)d_ws;
    const size_t NC = (size_t)N_NODES * CH;
    float* Q     = ws;
    float* K     = ws + NC;
    float* V     = ws + 2 * NC;
    float* S     = ws + 3 * NC;
    float* denom = ws + 4 * NC;

    // d_out / d_ws are poisoned 0xAA before every call — zero the accumulators
    hipMemsetAsync(out, 0, NC * sizeof(float), stream);
    hipMemsetAsync(denom, 0, (size_t)N_NODES * 2 * sizeof(float), stream);

    node_linear_kernel<<<N_NODES / 16, 256, 0, stream>>>(
        x, Wq, bq, Wk, bk, Wv, bv, Ws, bs, Q, K, V, S);

    edge_attn_kernel<<<N_EDGES / 64, 256, 0, stream>>>(
        last_update, t, msg, edge_index, W_time, b_time, We,
        Q, K, V, out, denom);

    finalize_kernel<<<(N_NODES * CH) / 256, 256, 0, stream>>>(S, denom, out);
}

// Round 2
// 1286.366 us; speedup vs baseline: 1.7587x; 1.7587x over previous
//
#include <hip/hip_runtime.h>
#include <math.h>

#define N_NODES 50000
#define N_EDGES 800000
#define CH 128        // IN_CH = OUT_CH = MSG_DIM = TIME_DIM = 128
#define GDIM 512      // 2 heads * 256 (G per-node vector)

// ---------------------------------------------------------------------------
// build_M: M[i][f] = sum_c Wq[i][h*64+c] * We[jj][h*64+c],  f = h*256+jj
// (the fused matrix s.t. G = x @ M + gbias gives q_h · e_h = edge_attr · G_h)
// ---------------------------------------------------------------------------
__global__ __launch_bounds__(256) void build_M_kernel(
    const float* __restrict__ Wq, const float* __restrict__ We,
    float* __restrict__ M)
{
    __shared__ float wq[CH];
    const int i = blockIdx.x, t = threadIdx.x;
    if (t < CH) wq[t] = Wq[i * CH + t];
    __syncthreads();
    #pragma unroll
    for (int rep = 0; rep < 2; ++rep) {
        int f  = rep * 256 + t;
        int h  = f >> 8, jj = f & 255;
        const float* wer = We + (size_t)jj * CH + h * 64;
        const float* wqr = wq + h * 64;
        float s = 0.f;
        #pragma unroll 8
        for (int c = 0; c < 64; ++c) s = fmaf(wqr[c], wer[c], s);
        M[(size_t)i * GDIM + f] = s;
    }
}

__global__ void build_gbias_kernel(const float* __restrict__ bq,
                                   const float* __restrict__ We,
                                   float* __restrict__ gb)
{
    int f = blockIdx.x * 256 + threadIdx.x;  // 512 total
    int h = f >> 8, jj = f & 255;
    float s = 0.f;
    #pragma unroll 8
    for (int c = 0; c < 64; ++c)
        s = fmaf(bq[h * 64 + c], We[(size_t)jj * CH + h * 64 + c], s);
    gb[f] = s;
}

// ---------------------------------------------------------------------------
// node_linear: Q,K,V,S = x@W+b (128 cols each), G = x@M+gb (512 cols).
// 64-node tile in LDS, register-tiled: thread owns 8 nodes x 4 cols per pass.
// ---------------------------------------------------------------------------
__global__ __launch_bounds__(256) void node_linear_kernel(
    const float* __restrict__ x,
    const float* __restrict__ Wq, const float* __restrict__ bq,
    const float* __restrict__ Wk, const float* __restrict__ bk,
    const float* __restrict__ Wv, const float* __restrict__ bv,
    const float* __restrict__ Ws, const float* __restrict__ bs,
    const float* __restrict__ M,  const float* __restrict__ gb,
    float* __restrict__ Q, float* __restrict__ K,
    float* __restrict__ V, float* __restrict__ S, float* __restrict__ G)
{
    __shared__ float xs[64][CH];
    const int t  = threadIdx.x;
    const int n0 = blockIdx.x * 64;

    #pragma unroll
    for (int r = 0; r < 8; ++r) {
        int flat4 = r * 256 + t;        // float4 index in 64x128 tile
        int row   = flat4 >> 5;
        int c4    = (flat4 & 31) * 4;
        int gr    = n0 + row; if (gr >= N_NODES) gr = N_NODES - 1;
        *(float4*)&xs[row][c4] = *(const float4*)&x[(size_t)gr * CH + c4];
    }
    __syncthreads();

    const int tx = t & 31, ey = t >> 5;
    const int c0 = tx * 4, e0 = ey * 8;

    const float* Wp[8]   = {Wq, Wk, Wv, Ws, M, M + 128, M + 256, M + 384};
    const int    wstr[8] = {CH, CH, CH, CH, GDIM, GDIM, GDIM, GDIM};
    const float* Bp[8]   = {bq, bk, bv, bs, gb, gb + 128, gb + 256, gb + 384};
    float*       Op[8]   = {Q, K, V, S, G, G + 128, G + 256, G + 384};
    const int    ostr[8] = {CH, CH, CH, CH, GDIM, GDIM, GDIM, GDIM};

    #pragma unroll
    for (int m = 0; m < 8; ++m) {
        const float* W = Wp[m];
        const int ws_ = wstr[m];
        float4 acc[8];
        #pragma unroll
        for (int i = 0; i < 8; ++i) acc[i] = make_float4(0.f, 0.f, 0.f, 0.f);
        for (int j = 0; j < CH; ++j) {
            float4 w = *(const float4*)&W[(size_t)j * ws_ + c0];
            #pragma unroll
            for (int i = 0; i < 8; ++i) {
                float a = xs[e0 + i][j];
                acc[i].x = fmaf(a, w.x, acc[i].x);
                acc[i].y = fmaf(a, w.y, acc[i].y);
                acc[i].z = fmaf(a, w.z, acc[i].z);
                acc[i].w = fmaf(a, w.w, acc[i].w);
            }
        }
        float4 b4 = *(const float4*)&Bp[m][c0];
        float* O  = Op[m];
        const int os = ostr[m];
        #pragma unroll
        for (int i = 0; i < 8; ++i) {
            int n = n0 + e0 + i;
            if (n < N_NODES) {
                float4 r = make_float4(acc[i].x + b4.x, acc[i].y + b4.y,
                                       acc[i].z + b4.z, acc[i].w + b4.w);
                *(float4*)&O[(size_t)n * os + c0] = r;
            }
        }
    }
}

// ---------------------------------------------------------------------------
// counting sort of edges by destination node
// ---------------------------------------------------------------------------
__global__ void hist_kernel(const int* __restrict__ ei, int* __restrict__ cnt)
{
    int e = blockIdx.x * 256 + threadIdx.x;
    atomicAdd(&cnt[ei[N_EDGES + e]], 1);
}

__global__ __launch_bounds__(1024) void scan_kernel(
    const int* __restrict__ cnt, int* __restrict__ base, int* __restrict__ cursor)
{
    __shared__ int ssum[1024];
    const int t = threadIdx.x;
    const int STRIP = 49;  // 1024*49 = 50176 >= N_NODES
    const int s0 = t * STRIP;
    int sum = 0;
    for (int i = 0; i < STRIP; ++i) {
        int idx = s0 + i;
        sum += (idx < N_NODES) ? cnt[idx] : 0;
    }
    ssum[t] = sum;
    __syncthreads();
    for (int off = 1; off < 1024; off <<= 1) {
        int v = (t >= off) ? ssum[t - off] : 0;
        __syncthreads();
        ssum[t] += v;
        __syncthreads();
    }
    int run = (t > 0) ? ssum[t - 1] : 0;
    for (int i = 0; i < STRIP; ++i) {
        int idx = s0 + i;
        if (idx < N_NODES) {
            base[idx] = run; cursor[idx] = run;
            run += cnt[idx];
        }
    }
    if (t == 1023) base[N_NODES] = ssum[1023];
}

__global__ void scatter_kernel(const int* __restrict__ ei, int* __restrict__ cursor,
                               int* __restrict__ ssrc, int* __restrict__ seid)
{
    int e = blockIdx.x * 256 + threadIdx.x;
    int d = ei[N_EDGES + e];
    int pos = atomicAdd(&cursor[d], 1);
    ssrc[pos] = ei[e];
    seid[pos] = e;
}

// ---------------------------------------------------------------------------
// gather_attn: one wave per destination node. Lane j owns edge_attr channels
// {j, j+64, j+128, j+192}.  Per edge: alpha = (q.k + ea.G)/8 via butterfly
// reduce, p = exp(alpha); accumulate denom, p*v, p*edge_attr in registers.
// Epilogue: wa -> LDS, project through We once per node, write out directly.
// ---------------------------------------------------------------------------
__global__ __launch_bounds__(256) void gather_attn_kernel(
    const float* __restrict__ last_update,
    const float* __restrict__ t_arr,
    const float* __restrict__ msg,
    const float* __restrict__ W_time,
    const float* __restrict__ b_time,
    const float* __restrict__ We,
    const float* __restrict__ Q, const float* __restrict__ K,
    const float* __restrict__ V, const float* __restrict__ S,
    const float* __restrict__ G,
    const int* __restrict__ base, const int* __restrict__ ssrc,
    const int* __restrict__ seid,
    float* __restrict__ out)
{
    __shared__ float wabuf[4][GDIM];
    const int wv = threadIdx.x >> 6;
    const int j  = threadIdx.x & 63;
    const int n  = blockIdx.x * 4 + wv;

    const float q0 = Q[(size_t)n * CH + j];
    const float q1 = Q[(size_t)n * CH + 64 + j];
    const float* gn = G + (size_t)n * GDIM + j;
    const float g00 = gn[0],   g01 = gn[64],  g02 = gn[128], g03 = gn[192];
    const float g10 = gn[256], g11 = gn[320], g12 = gn[384], g13 = gn[448];
    const float wt0 = W_time[j], wt1 = W_time[64 + j];
    const float bt0 = b_time[j], bt1 = b_time[64 + j];

    float wa00 = 0.f, wa01 = 0.f, wa02 = 0.f, wa03 = 0.f;
    float wa10 = 0.f, wa11 = 0.f, wa12 = 0.f, wa13 = 0.f;
    float nv0 = 0.f, nv1 = 0.f, den0 = 0.f, den1 = 0.f;

    const int b0 = base[n], b1 = base[n + 1];
    for (int i = b0; i < b1; ++i) {
        int src = ssrc[i];
        int eid = seid[i];
        float rt  = last_update[src] - t_arr[eid];
        float ea0 = __cosf(fmaf(rt, wt0, bt0));
        float ea1 = __cosf(fmaf(rt, wt1, bt1));
        float ea2 = msg[(size_t)eid * CH + j];
        float ea3 = msg[(size_t)eid * CH + 64 + j];
        float k0  = K[(size_t)src * CH + j];
        float k1  = K[(size_t)src * CH + 64 + j];
        float v0  = V[(size_t)src * CH + j];
        float v1  = V[(size_t)src * CH + 64 + j];

        float p0 = q0 * k0 + ea0 * g00 + ea1 * g01 + ea2 * g02 + ea3 * g03;
        float p1 = q1 * k1 + ea0 * g10 + ea1 * g11 + ea2 * g12 + ea3 * g13;
        p0 += __shfl_xor(p0, 1);  p1 += __shfl_xor(p1, 1);
        p0 += __shfl_xor(p0, 2);  p1 += __shfl_xor(p1, 2);
        p0 += __shfl_xor(p0, 4);  p1 += __shfl_xor(p1, 4);
        p0 += __shfl_xor(p0, 8);  p1 += __shfl_xor(p1, 8);
        p0 += __shfl_xor(p0, 16); p1 += __shfl_xor(p1, 16);
        p0 += __shfl_xor(p0, 32); p1 += __shfl_xor(p1, 32);
        p0 = __expf(p0 * 0.125f);
        p1 = __expf(p1 * 0.125f);

        den0 += p0; den1 += p1;
        wa00 = fmaf(p0, ea0, wa00); wa01 = fmaf(p0, ea1, wa01);
        wa02 = fmaf(p0, ea2, wa02); wa03 = fmaf(p0, ea3, wa03);
        wa10 = fmaf(p1, ea0, wa10); wa11 = fmaf(p1, ea1, wa11);
        wa12 = fmaf(p1, ea2, wa12); wa13 = fmaf(p1, ea3, wa13);
        nv0  = fmaf(p0, v0, nv0);
        nv1  = fmaf(p1, v1, nv1);
    }

    wabuf[wv][j]       = wa00; wabuf[wv][64 + j]  = wa01;
    wabuf[wv][128 + j] = wa02; wabuf[wv][192 + j] = wa03;
    wabuf[wv][256 + j] = wa10; wabuf[wv][320 + j] = wa11;
    wabuf[wv][384 + j] = wa12; wabuf[wv][448 + j] = wa13;
    __syncthreads();

    float a0 = 0.f, a1 = 0.f;
    #pragma unroll 4
    for (int jj = 0; jj < 256; ++jj) {
        float w0 = wabuf[wv][jj];
        float w1 = wabuf[wv][256 + jj];
        a0 = fmaf(w0, We[(size_t)jj * CH + j], a0);
        a1 = fmaf(w1, We[(size_t)jj * CH + 64 + j], a1);
    }

    float r0 = (b1 > b0) ? (nv0 + a0) / den0 : 0.f;
    float r1 = (b1 > b0) ? (nv1 + a1) / den1 : 0.f;
    out[(size_t)n * CH + j]      = r0 + S[(size_t)n * CH + j];
    out[(size_t)n * CH + 64 + j] = r1 + S[(size_t)n * CH + 64 + j];
}

extern "C" void kernel_launch(void* const* d_in, const int* in_sizes, int n_in,
                              void* d_out, int out_size, void* d_ws, size_t ws_size,
                              hipStream_t stream) {
    const float* x           = (const float*)d_in[0];
    const float* last_update = (const float*)d_in[1];
    const float* t           = (const float*)d_in[2];
    const float* msg         = (const float*)d_in[3];
    const int*   edge_index  = (const int*)d_in[4];
    const float* W_time      = (const float*)d_in[5];
    const float* b_time      = (const float*)d_in[6];
    const float* Wq = (const float*)d_in[7];
    const float* bq = (const float*)d_in[8];
    const float* Wk = (const float*)d_in[9];
    const float* bk = (const float*)d_in[10];
    const float* Wv = (const float*)d_in[11];
    const float* bv = (const float*)d_in[12];
    const float* We = (const float*)d_in[13];
    const float* Ws = (const float*)d_in[14];
    const float* bs = (const float*)d_in[15];
    float* out = (float*)d_out;

    float* ws = (float*)d_ws;
    const size_t NC = (size_t)N_NODES * CH;
    float* Q  = ws;
    float* K  = Q + NC;
    float* V  = K + NC;
    float* S  = V + NC;
    float* G  = S + NC;                            // N*512
    float* M  = G + (size_t)N_NODES * GDIM;        // 128*512
    float* gb = M + (size_t)CH * GDIM;             // 512
    int* cnt    = (int*)(gb + GDIM);
    int* base   = cnt + N_NODES;
    int* cursor = base + N_NODES + 1;
    int* ssrc   = cursor + N_NODES;
    int* seid   = ssrc + N_EDGES;

    hipMemsetAsync(cnt, 0, (size_t)N_NODES * sizeof(int), stream);

    build_M_kernel<<<CH, 256, 0, stream>>>(Wq, We, M);
    build_gbias_kernel<<<2, 256, 0, stream>>>(bq, We, gb);

    node_linear_kernel<<<(N_NODES + 63) / 64, 256, 0, stream>>>(
        x, Wq, bq, Wk, bk, Wv, bv, Ws, bs, M, gb, Q, K, V, S, G);

    hist_kernel<<<N_EDGES / 256, 256, 0, stream>>>(edge_index, cnt);
    scan_kernel<<<1, 1024, 0, stream>>>(cnt, base, cursor);
    scatter_kernel<<<N_EDGES / 256, 256, 0, stream>>>(edge_index, cursor, ssrc, seid);

    gather_attn_kernel<<<N_NODES / 4, 256, 0, stream>>>(
        last_update, t, msg, W_time, b_time, We,
        Q, K, V, S, G, base, ssrc, seid, out);
}